// Round 4
// baseline (482.879 us; speedup 1.0000x reference)
//
#include <hip/hip_runtime.h>

#define VOCAB 32000
#define EMB 64
#define NROWS 8192                // B*S
#define NCHUNKS 50
#define CCOLS (VOCAB / NCHUNKS)   // 640
#define CTILES (CCOLS / 16)       // 40
#define ROWS_PER_BLOCK 512        // 4 waves x 128 rows
#define CAND_MAX 131072

typedef __attribute__((ext_vector_type(8))) short bf16x8;
typedef __attribute__((ext_vector_type(4))) float f32x4;
typedef float f4nt __attribute__((ext_vector_type(4)));

// Monotone order-preserving f32 -> u32 (equal floats -> equal keys).
__device__ __forceinline__ unsigned enc_f32(float f) {
    unsigned u = __float_as_uint(f);
    return (u & 0x80000000u) ? ~u : (u | 0x80000000u);
}
__device__ __forceinline__ float dec_f32(unsigned e) {
    unsigned u = (e & 0x80000000u) ? (e & 0x7fffffffu) : ~e;
    return __uint_as_float(u);
}
// f32 -> bf16 round-to-nearest-even (inputs Gaussian: no NaN/Inf).
__device__ __forceinline__ unsigned short f2bf(float f) {
    unsigned u = __float_as_uint(f);
    return (unsigned short)((u + 0x7fffu + ((u >> 16) & 1u)) >> 16);
}

// ---- setup: WB16 = bf16(W*invn), A16 = bf16(x), norms, init scratch ----
__global__ __launch_bounds__(256) void setup_kernel(
    const float* __restrict__ x, const float* __restrict__ W,
    unsigned short* __restrict__ A16, unsigned short* __restrict__ WB16,
    float* __restrict__ invn, float* __restrict__ normA,
    unsigned* __restrict__ rowmax, unsigned long long* __restrict__ fin,
    unsigned* __restrict__ counter)
{
    int i = blockIdx.x * blockDim.x + threadIdx.x;
    if (i == 0) *counter = 0u;
    if (i < NROWS) { rowmax[i] = 0u; fin[i] = 0ull; }
    if (i < VOCAB) {
        const float4* w4 = (const float4*)(W + (size_t)i * EMB);
        float4 buf[16];
        float s = 0.f;
        #pragma unroll
        for (int q = 0; q < 16; ++q) {
            float4 w = w4[q]; buf[q] = w;
            s += w.x * w.x + w.y * w.y + w.z * w.z + w.w * w.w;
        }
        float inv = 1.0f / sqrtf(s);
        invn[i] = inv;
        ushort4* dst = (ushort4*)(WB16 + (size_t)i * EMB);
        #pragma unroll
        for (int q = 0; q < 16; ++q) {
            float4 w = buf[q];
            ushort4 u;
            u.x = f2bf(w.x * inv); u.y = f2bf(w.y * inv);
            u.z = f2bf(w.z * inv); u.w = f2bf(w.w * inv);
            dst[q] = u;
        }
    }
    if (i < NROWS) {
        const float4* a4 = (const float4*)(x + (size_t)i * EMB);
        float4 buf[16];
        float s = 0.f;
        #pragma unroll
        for (int q = 0; q < 16; ++q) {
            float4 a = a4[q]; buf[q] = a;
            s += a.x * a.x + a.y * a.y + a.z * a.z + a.w * a.w;
        }
        normA[i] = sqrtf(s);
        ushort4* dst = (ushort4*)(A16 + (size_t)i * EMB);
        #pragma unroll
        for (int q = 0; q < 16; ++q) {
            float4 a = buf[q];
            ushort4 u;
            u.x = f2bf(a.x); u.y = f2bf(a.y); u.z = f2bf(a.z); u.w = f2bf(a.w);
            dst[q] = u;
        }
    }
}

// ---- pass 1: per-row max of approx sims (bf16 MFMA, 128 rows/wave) ----
// Fragment maps (gfx950 16x16x32 bf16, m89/m92-verified):
// A/B lane l: idx = l&15, k0 = (l>>4)*8 (8 contiguous k);
// C/D lane l: col = l&15, row = (l>>4)*4 + reg.
__global__ __launch_bounds__(256) void pass1_kernel(
    const unsigned short* __restrict__ A16,
    const unsigned short* __restrict__ WB16,
    unsigned* __restrict__ rowmax)
{
    const int lane = threadIdx.x & 63, wid = threadIdx.x >> 6;
    const int lr = lane & 15, lg = lane >> 4;
    const int m0 = blockIdx.x * ROWS_PER_BLOCK + wid * 128;
    const int n0 = blockIdx.y * CCOLS;

    bf16x8 a[8][2];
    #pragma unroll
    for (int r = 0; r < 8; ++r)
        #pragma unroll
        for (int kk = 0; kk < 2; ++kk)
            a[r][kk] = *(const bf16x8*)(A16 + (size_t)(m0 + r * 16 + lr) * EMB + kk * 32 + lg * 8);

    float best[8][4];
    #pragma unroll
    for (int r = 0; r < 8; ++r)
        #pragma unroll
        for (int j = 0; j < 4; ++j) best[r][j] = -3e38f;

    const unsigned short* wb = WB16 + (size_t)(n0 + lr) * EMB + lg * 8;
    bf16x8 b0 = *(const bf16x8*)(wb);
    bf16x8 b1 = *(const bf16x8*)(wb + 32);
    for (int t = 0; t < CTILES; ++t) {
        // prefetch next tile (last iter reads 2KB past WB16 into A16: harmless)
        const unsigned short* wn = wb + 16 * EMB;
        bf16x8 nb0 = *(const bf16x8*)(wn);
        bf16x8 nb1 = *(const bf16x8*)(wn + 32);
        #pragma unroll
        for (int r = 0; r < 8; ++r) {
            f32x4 acc = {0.f, 0.f, 0.f, 0.f};
            acc = __builtin_amdgcn_mfma_f32_16x16x32_bf16(a[r][0], b0, acc, 0, 0, 0);
            acc = __builtin_amdgcn_mfma_f32_16x16x32_bf16(a[r][1], b1, acc, 0, 0, 0);
            #pragma unroll
            for (int j = 0; j < 4; ++j) best[r][j] = fmaxf(best[r][j], acc[j]);
        }
        b0 = nb0; b1 = nb1;
        wb = wn;
    }
    #pragma unroll
    for (int r = 0; r < 8; ++r)
        #pragma unroll
        for (int j = 0; j < 4; ++j) {
            float v = best[r][j];
            v = fmaxf(v, __shfl_xor(v, 1));
            v = fmaxf(v, __shfl_xor(v, 2));
            v = fmaxf(v, __shfl_xor(v, 4));
            v = fmaxf(v, __shfl_xor(v, 8));
            if (lr == 0) atomicMax(&rowmax[m0 + r * 16 + lg * 4 + j], enc_f32(v));
        }
}

// ---- pass 2: recompute (bitwise-identical) + collect candidates ----
// thr = global_approx_max - 0.009*|A| (bound: 2*2^-8*|A| = 0.0078, 15% slack)
__global__ __launch_bounds__(256) void pass2_kernel(
    const unsigned short* __restrict__ A16,
    const unsigned short* __restrict__ WB16,
    const unsigned* __restrict__ rowmax, const float* __restrict__ normA,
    unsigned* __restrict__ counter, uint2* __restrict__ cand)
{
    const int lane = threadIdx.x & 63, wid = threadIdx.x >> 6;
    const int lr = lane & 15, lg = lane >> 4;
    const int m0 = blockIdx.x * ROWS_PER_BLOCK + wid * 128;
    const int n0 = blockIdx.y * CCOLS;

    bf16x8 a[8][2];
    #pragma unroll
    for (int r = 0; r < 8; ++r)
        #pragma unroll
        for (int kk = 0; kk < 2; ++kk)
            a[r][kk] = *(const bf16x8*)(A16 + (size_t)(m0 + r * 16 + lr) * EMB + kk * 32 + lg * 8);

    float thr[8][4];
    #pragma unroll
    for (int r = 0; r < 8; ++r)
        #pragma unroll
        for (int j = 0; j < 4; ++j) {
            int row = m0 + r * 16 + lg * 4 + j;
            thr[r][j] = dec_f32(rowmax[row]) - 0.009f * normA[row];
        }

    const unsigned short* wb = WB16 + (size_t)(n0 + lr) * EMB + lg * 8;
    bf16x8 b0 = *(const bf16x8*)(wb);
    bf16x8 b1 = *(const bf16x8*)(wb + 32);
    for (int t = 0; t < CTILES; ++t) {
        const unsigned short* wn = wb + 16 * EMB;
        bf16x8 nb0 = *(const bf16x8*)(wn);
        bf16x8 nb1 = *(const bf16x8*)(wn + 32);
        f32x4 accs[8];
        float mx = -1.f;
        #pragma unroll
        for (int r = 0; r < 8; ++r) {
            f32x4 acc = {0.f, 0.f, 0.f, 0.f};
            acc = __builtin_amdgcn_mfma_f32_16x16x32_bf16(a[r][0], b0, acc, 0, 0, 0);
            acc = __builtin_amdgcn_mfma_f32_16x16x32_bf16(a[r][1], b1, acc, 0, 0, 0);
            accs[r] = acc;
            #pragma unroll
            for (int j = 0; j < 4; ++j) mx = fmaxf(mx, acc[j] - thr[r][j]);
        }
        if (mx >= 0.f) {   // rare (~1 in 6000 lanes)
            #pragma unroll
            for (int r = 0; r < 8; ++r)
                #pragma unroll
                for (int j = 0; j < 4; ++j)
                    if (accs[r][j] >= thr[r][j]) {
                        unsigned pos = atomicAdd(counter, 1u);
                        if (pos < CAND_MAX)
                            cand[pos] = make_uint2((unsigned)(m0 + r * 16 + lg * 4 + j),
                                                   (unsigned)(n0 + t * 16 + lr));
                    }
        }
        b0 = nb0; b1 = nb1;
        wb = wn;
    }
}

// ---- pass 3: exact fp32 re-score of candidates, packed argmax ----
__global__ __launch_bounds__(256) void pass3_kernel(
    const float* __restrict__ x, const float* __restrict__ W,
    const float* __restrict__ invn, const unsigned* __restrict__ counter,
    const uint2* __restrict__ cand, unsigned long long* __restrict__ fin)
{
    unsigned cnt = *counter;
    if (cnt > CAND_MAX) cnt = CAND_MAX;
    for (unsigned i = blockIdx.x * blockDim.x + threadIdx.x; i < cnt;
         i += gridDim.x * blockDim.x) {
        unsigned row = cand[i].x, v = cand[i].y;
        const float4* a4 = (const float4*)(x + (size_t)row * EMB);
        const float4* w4 = (const float4*)(W + (size_t)v * EMB);
        float p0 = 0.f, p1 = 0.f, p2 = 0.f, p3 = 0.f;
        #pragma unroll
        for (int q = 0; q < 16; ++q) {
            float4 aa = a4[q]; float4 ww = w4[q];
            p0 = fmaf(aa.x, ww.x, p0);
            p1 = fmaf(aa.y, ww.y, p1);
            p2 = fmaf(aa.z, ww.z, p2);
            p3 = fmaf(aa.w, ww.w, p3);
        }
        float s = ((p0 + p1) + (p2 + p3)) * invn[v];
        // larger sim wins; equal sim -> larger ~v = smaller v (numpy tie-break)
        unsigned long long k = ((unsigned long long)enc_f32(s) << 32) | (unsigned)(~v);
        atomicMax(&fin[row], k);
    }
}

// ---- zero-stream: 1.048 GB of zeros, pure nontemporal float4 ----
__global__ __launch_bounds__(256) void zero_kernel(float4* __restrict__ out) {
    const unsigned total = (unsigned)NROWS * (VOCAB / 4);   // 65,536,000
    const f4nt z = {0.f, 0.f, 0.f, 0.f};
    unsigned i = blockIdx.x * blockDim.x + threadIdx.x;
    const unsigned stride = gridDim.x * blockDim.x;
    for (; i < total; i += stride)
        __builtin_nontemporal_store(z, (f4nt*)&out[i]);
}

// ---- scatter the 8192 ones ----
__global__ void scatter_kernel(const unsigned long long* __restrict__ fin,
                               float* __restrict__ out) {
    int row = blockIdx.x * blockDim.x + threadIdx.x;
    if (row < NROWS) {
        unsigned idx = ~(unsigned)fin[row];
        out[(size_t)row * VOCAB + idx] = 1.0f;
    }
}

extern "C" void kernel_launch(void* const* d_in, const int* in_sizes, int n_in,
                              void* d_out, int out_size, void* d_ws, size_t ws_size,
                              hipStream_t stream) {
    const float* x = (const float*)d_in[0];   // [2,4096,64]
    const float* W = (const float*)d_in[1];   // [32000,64]
    float* out = (float*)d_out;

    char* ws = (char*)d_ws;
    unsigned short* WB16  = (unsigned short*)(ws);                    // 4,096,000
    unsigned short* A16   = (unsigned short*)(ws + 4096000);          // 1,048,576
    float* invn           = (float*)(ws + 5144576);                   //   128,000
    float* normA          = (float*)(ws + 5272576);                   //    32,768
    unsigned* rowmax      = (unsigned*)(ws + 5305344);                //    32,768
    unsigned long long* fin = (unsigned long long*)(ws + 5370880);    //    65,536
    unsigned* counter     = (unsigned*)(ws + 5436416);                //        16
    uint2* cand           = (uint2*)(ws + 5436432);                   // 1,048,576

    setup_kernel<<<dim3((VOCAB + 255) / 256), dim3(256), 0, stream>>>(
        x, W, A16, WB16, invn, normA, rowmax, fin, counter);

    pass1_kernel<<<dim3(NROWS / ROWS_PER_BLOCK, NCHUNKS), dim3(256), 0, stream>>>(
        A16, WB16, rowmax);

    pass2_kernel<<<dim3(NROWS / ROWS_PER_BLOCK, NCHUNKS), dim3(256), 0, stream>>>(
        A16, WB16, rowmax, normA, counter, cand);

    pass3_kernel<<<dim3(64), dim3(256), 0, stream>>>(x, W, invn, counter, cand, fin);

    zero_kernel<<<dim3(4096), dim3(256), 0, stream>>>((float4*)out);

    scatter_kernel<<<dim3((NROWS + 255) / 256), dim3(256), 0, stream>>>(fin, out);
}

// Round 5
// 404.131 us; speedup vs baseline: 1.1949x; 1.1949x over previous
//
#include <hip/hip_runtime.h>

#define VOCAB 32000
#define EMB 64
#define NROWS 8192                // B*S
#define NCHUNKS 50
#define CCOLS 640                 // VOCAB / NCHUNKS
#define CTILES 40                 // CCOLS / 16
#define NSUB 500                  // VOCAB / 64 subchunks of 64 cols
#define SUBPAD 512
#define LIST_MAX 32768

typedef __attribute__((ext_vector_type(8))) short bf16x8;
typedef __attribute__((ext_vector_type(4))) float f32x4;
typedef float f4nt __attribute__((ext_vector_type(4)));

// Monotone order-preserving f32 -> u32 (equal floats -> equal keys).
__device__ __forceinline__ unsigned enc_f32(float f) {
    unsigned u = __float_as_uint(f);
    return (u & 0x80000000u) ? ~u : (u | 0x80000000u);
}
__device__ __forceinline__ float dec_f32(unsigned e) {
    unsigned u = (e & 0x80000000u) ? (e & 0x7fffffffu) : ~e;
    return __uint_as_float(u);
}
// f32 -> bf16 round-to-nearest-even (inputs Gaussian: no NaN/Inf).
__device__ __forceinline__ unsigned short f2bf(float f) {
    unsigned u = __float_as_uint(f);
    return (unsigned short)((u + 0x7fffu + ((u >> 16) & 1u)) >> 16);
}

// ---- setup: WB16 = bf16(W*invn), A16 = bf16(x), norms, init fin/counter ----
// (norm accumulation order identical to rounds 1-4: exact path unchanged)
__global__ __launch_bounds__(256) void setup_kernel(
    const float* __restrict__ x, const float* __restrict__ W,
    unsigned short* __restrict__ A16, unsigned short* __restrict__ WB16,
    float* __restrict__ invn, float* __restrict__ normA,
    unsigned long long* __restrict__ fin, unsigned* __restrict__ counter)
{
    int i = blockIdx.x * blockDim.x + threadIdx.x;
    if (i == 0) *counter = 0u;
    if (i < NROWS) fin[i] = 0ull;
    if (i < VOCAB) {
        const float4* w4 = (const float4*)(W + (size_t)i * EMB);
        float4 buf[16];
        float s = 0.f;
        #pragma unroll
        for (int q = 0; q < 16; ++q) {
            float4 w = w4[q]; buf[q] = w;
            s += w.x * w.x + w.y * w.y + w.z * w.z + w.w * w.w;
        }
        float inv = 1.0f / sqrtf(s);
        invn[i] = inv;
        ushort4* dst = (ushort4*)(WB16 + (size_t)i * EMB);
        #pragma unroll
        for (int q = 0; q < 16; ++q) {
            float4 w = buf[q];
            ushort4 u;
            u.x = f2bf(w.x * inv); u.y = f2bf(w.y * inv);
            u.z = f2bf(w.z * inv); u.w = f2bf(w.w * inv);
            dst[q] = u;
        }
    }
    if (i < NROWS) {
        const float4* a4 = (const float4*)(x + (size_t)i * EMB);
        float4 buf[16];
        float s = 0.f;
        #pragma unroll
        for (int q = 0; q < 16; ++q) {
            float4 a = a4[q]; buf[q] = a;
            s += a.x * a.x + a.y * a.y + a.z * a.z + a.w * a.w;
        }
        normA[i] = sqrtf(s);
        ushort4* dst = (ushort4*)(A16 + (size_t)i * EMB);
        #pragma unroll
        for (int q = 0; q < 16; ++q) {
            float4 a = buf[q];
            ushort4 u;
            u.x = f2bf(a.x); u.y = f2bf(a.y); u.z = f2bf(a.z); u.w = f2bf(a.w);
            dst[q] = u;
        }
    }
}

// ---- pass1: bf16-MFMA approx sims -> per-(row,64col-sub) u16 max,
//             FUSED with the 1.048 GB zero-stream of the output ----
// 4 frags/wave (64 rows) keeps VGPR ~100 (round-4 post-mortem: 8 frags spilled
// TLP). Fragment maps (m89/m92-verified): A/B lane l: idx=l&15, k0=(l>>4)*8;
// C/D: col=l&15, row=(l>>4)*4+reg. Truncated-u16 pval only LOWERS maxima ->
// pruning stays conservative.
__global__ __launch_bounds__(256) void pass1_kernel(
    const unsigned short* __restrict__ A16,
    const unsigned short* __restrict__ WB16,
    unsigned short* __restrict__ pval, float4* __restrict__ out4)
{
    const int lane = threadIdx.x & 63, wid = threadIdx.x >> 6;
    const int lr = lane & 15, lg = lane >> 4;
    const int m0 = blockIdx.x * 256 + wid * 64;
    const int n0 = blockIdx.y * CCOLS;

    // zero-stream: block covers out4[blin*40960 .. +40960)
    const int blin = blockIdx.x + blockIdx.y * 32;     // 0..1599
    float4* ob = out4 + (size_t)blin * (CTILES * 1024) + threadIdx.x;
    const f4nt z = {0.f, 0.f, 0.f, 0.f};

    bf16x8 a[4][2];
    #pragma unroll
    for (int r = 0; r < 4; ++r)
        #pragma unroll
        for (int kk = 0; kk < 2; ++kk)
            a[r][kk] = *(const bf16x8*)(A16 + (size_t)(m0 + r * 16 + lr) * EMB + kk * 32 + lg * 8);

    float best[4][4];
    #pragma unroll
    for (int r = 0; r < 4; ++r)
        #pragma unroll
        for (int j = 0; j < 4; ++j) best[r][j] = -3e38f;

    const unsigned short* wb = WB16 + (size_t)(n0 + lr) * EMB + lg * 8;
    bf16x8 b0 = *(const bf16x8*)(wb);
    bf16x8 b1 = *(const bf16x8*)(wb + 32);
    for (int t = 0; t < CTILES; ++t) {
        // prefetch next 16-col tile (last iter overruns 2KB into A16: harmless)
        const unsigned short* wn = wb + 16 * EMB;
        bf16x8 nb0 = *(const bf16x8*)(wn);
        bf16x8 nb1 = *(const bf16x8*)(wn + 32);
        // 4 nontemporal zero-stores per thread per iter (exactly covers out)
        #pragma unroll
        for (int k = 0; k < 4; ++k)
            __builtin_nontemporal_store(z, (f4nt*)(ob + t * 1024 + k * 256));
        #pragma unroll
        for (int r = 0; r < 4; ++r) {
            f32x4 acc = {0.f, 0.f, 0.f, 0.f};
            acc = __builtin_amdgcn_mfma_f32_16x16x32_bf16(a[r][0], b0, acc, 0, 0, 0);
            acc = __builtin_amdgcn_mfma_f32_16x16x32_bf16(a[r][1], b1, acc, 0, 0, 0);
            #pragma unroll
            for (int j = 0; j < 4; ++j) best[r][j] = fmaxf(best[r][j], acc[j]);
        }
        if ((t & 3) == 3) {   // subchunk (64 cols) boundary: reduce + store
            const int sub = blockIdx.y * 10 + (t >> 2);
            #pragma unroll
            for (int r = 0; r < 4; ++r)
                #pragma unroll
                for (int j = 0; j < 4; ++j) {
                    float v = best[r][j];
                    v = fmaxf(v, __shfl_xor(v, 1));
                    v = fmaxf(v, __shfl_xor(v, 2));
                    v = fmaxf(v, __shfl_xor(v, 4));
                    v = fmaxf(v, __shfl_xor(v, 8));
                    if (lr == 0)
                        pval[(size_t)(m0 + r * 16 + lg * 4 + j) * SUBPAD + sub] =
                            (unsigned short)(enc_f32(v) >> 16);
                    best[r][j] = -3e38f;
                }
        }
        b0 = nb0; b1 = nb1;
        wb = wn;
    }
}

// ---- select: per row, rebuild max from pval, threshold, append survivors ----
// thr = max_approx - 0.009*|A| (2*2^-8*|A| bound + 15% slack, proven r3/r4).
// u16 compare uses (val+1)<<16 > thr_enc: never false-prunes a truncated max.
__global__ __launch_bounds__(64) void select_kernel(
    const unsigned short* __restrict__ pval, const float* __restrict__ normA,
    unsigned* __restrict__ counter, unsigned* __restrict__ list)
{
    const int row = blockIdx.x;
    const int lane = threadIdx.x;
    const unsigned short* pr = pval + (size_t)row * SUBPAD + lane * 8;
    ushort4 v0 = *(const ushort4*)(pr);
    ushort4 v1 = *(const ushort4*)(pr + 4);
    unsigned short vals[8] = {v0.x, v0.y, v0.z, v0.w, v1.x, v1.y, v1.z, v1.w};

    unsigned mx = 0;
    #pragma unroll
    for (int k = 0; k < 8; ++k)
        if (lane * 8 + k < NSUB) mx = mx > vals[k] ? mx : (unsigned)vals[k];
    #pragma unroll
    for (int off = 1; off < 64; off <<= 1) {
        unsigned o = __shfl_xor(mx, off);
        mx = mx > o ? mx : o;
    }
    float thr = dec_f32(mx << 16) - 0.009f * normA[row];
    unsigned thr_enc = enc_f32(thr);
    #pragma unroll
    for (int k = 0; k < 8; ++k) {
        int sub = lane * 8 + k;
        if (sub < NSUB && (((unsigned)vals[k] + 1u) << 16) > thr_enc) {
            unsigned pos = atomicAdd(counter, 1u);
            if (pos < LIST_MAX) list[pos] = ((unsigned)sub << 16) | (unsigned)row;
        }
    }
}

// ---- rescore: exact fp32 dots (order identical to rounds 1-4) on survivors ----
__global__ __launch_bounds__(256) void rescore_kernel(
    const float* __restrict__ x, const float* __restrict__ W,
    const float* __restrict__ invn, const unsigned* __restrict__ counter,
    const unsigned* __restrict__ list, unsigned long long* __restrict__ fin)
{
    unsigned cnt = *counter;
    if (cnt > LIST_MAX) cnt = LIST_MAX;
    const int lane = threadIdx.x & 63;
    const unsigned gw = (blockIdx.x * 256 + threadIdx.x) >> 6;
    const unsigned nw = (gridDim.x * 256) >> 6;
    for (unsigned e = gw; e < cnt; e += nw) {
        unsigned ent = list[e];
        unsigned row = ent & 0xFFFFu, sub = ent >> 16;
        unsigned v = sub * 64 + lane;
        const float4* a4 = (const float4*)(x + (size_t)row * EMB);
        const float4* w4 = (const float4*)(W + (size_t)v * EMB);
        float p0 = 0.f, p1 = 0.f, p2 = 0.f, p3 = 0.f;
        #pragma unroll
        for (int q = 0; q < 16; ++q) {
            float4 aa = a4[q]; float4 ww = w4[q];
            p0 = fmaf(aa.x, ww.x, p0);
            p1 = fmaf(aa.y, ww.y, p1);
            p2 = fmaf(aa.z, ww.z, p2);
            p3 = fmaf(aa.w, ww.w, p3);
        }
        float s = ((p0 + p1) + (p2 + p3)) * invn[v];
        // larger sim wins; equal sim -> larger ~v = smaller v (numpy tie-break)
        unsigned long long k = ((unsigned long long)enc_f32(s) << 32) | (unsigned)(~v);
        #pragma unroll
        for (int off = 1; off < 64; off <<= 1) {
            unsigned long long o = __shfl_xor(k, off);
            k = k > o ? k : o;
        }
        if (lane == 0) atomicMax(&fin[row], k);
    }
}

// ---- scatter the 8192 ones (out already zeroed by pass1's fused stream) ----
__global__ void scatter_kernel(const unsigned long long* __restrict__ fin,
                               float* __restrict__ out) {
    int row = blockIdx.x * blockDim.x + threadIdx.x;
    if (row < NROWS) {
        unsigned idx = ~(unsigned)fin[row];
        out[(size_t)row * VOCAB + idx] = 1.0f;
    }
}

extern "C" void kernel_launch(void* const* d_in, const int* in_sizes, int n_in,
                              void* d_out, int out_size, void* d_ws, size_t ws_size,
                              hipStream_t stream) {
    const float* x = (const float*)d_in[0];   // [2,4096,64]
    const float* W = (const float*)d_in[1];   // [32000,64]
    float* out = (float*)d_out;

    char* ws = (char*)d_ws;
    unsigned short* WB16    = (unsigned short*)(ws);                 // 4,096,000
    unsigned short* A16     = (unsigned short*)(ws + 4096000);       // 1,048,576
    float* invn             = (float*)(ws + 5144576);                //   128,000
    float* normA            = (float*)(ws + 5272576);                //    32,768
    unsigned long long* fin = (unsigned long long*)(ws + 5305344);   //    65,536
    unsigned* counter       = (unsigned*)(ws + 5370880);             //        64
    unsigned* list          = (unsigned*)(ws + 5370944);             //   131,072
    unsigned short* pval    = (unsigned short*)(ws + 5502016);       // 8,388,608
    // total ws use: 13,890,624 B

    setup_kernel<<<dim3((VOCAB + 255) / 256), dim3(256), 0, stream>>>(
        x, W, A16, WB16, invn, normA, fin, counter);

    pass1_kernel<<<dim3(NROWS / 256, NCHUNKS), dim3(256), 0, stream>>>(
        A16, WB16, pval, (float4*)out);

    select_kernel<<<dim3(NROWS), dim3(64), 0, stream>>>(pval, normA, counter, list);

    rescore_kernel<<<dim3(2048), dim3(256), 0, stream>>>(x, W, invn, counter, list, fin);

    scatter_kernel<<<dim3((NROWS + 255) / 256), dim3(256), 0, stream>>>(fin, out);
}

// Round 6
// 262.255 us; speedup vs baseline: 1.8413x; 1.5410x over previous
//
#include <hip/hip_runtime.h>

#define VOCAB 32000
#define EMB 64
#define NROWS 8192                // B*S
#define NCHUNKS 50
#define CCOLS 640                 // VOCAB / NCHUNKS
#define CTILES 40                 // CCOLS / 16
#define NSUB 500                  // VOCAB / 64 subchunks of 64 cols
#define SUBPAD 512
#define NZ_BLOCKS 2048            // pure-zero blocks (512 KB each)
#define PAT 57                    // per 57 blocks: 25 compute + 32 zero
#define TOTAL_BLOCKS 3648         // 64 * 57 -> 1600 compute + 2048 zero

typedef __attribute__((ext_vector_type(8))) short bf16x8;
typedef __attribute__((ext_vector_type(4))) float f32x4;
typedef float f4nt __attribute__((ext_vector_type(4)));

// Monotone order-preserving f32 -> u32 (equal floats -> equal keys).
__device__ __forceinline__ unsigned enc_f32(float f) {
    unsigned u = __float_as_uint(f);
    return (u & 0x80000000u) ? ~u : (u | 0x80000000u);
}
__device__ __forceinline__ float dec_f32(unsigned e) {
    unsigned u = (e & 0x80000000u) ? (e & 0x7fffffffu) : ~e;
    return __uint_as_float(u);
}
// f32 -> bf16 round-to-nearest-even (inputs Gaussian: no NaN/Inf).
__device__ __forceinline__ unsigned short f2bf(float f) {
    unsigned u = __float_as_uint(f);
    return (unsigned short)((u + 0x7fffu + ((u >> 16) & 1u)) >> 16);
}

// ---- setup: WB16 = bf16(W*invn), A16 = bf16(x), norms ----
// (norm accumulation order identical to rounds 1-5: exact path unchanged)
__global__ __launch_bounds__(256) void setup_kernel(
    const float* __restrict__ x, const float* __restrict__ W,
    unsigned short* __restrict__ A16, unsigned short* __restrict__ WB16,
    float* __restrict__ invn, float* __restrict__ normA)
{
    int i = blockIdx.x * blockDim.x + threadIdx.x;
    if (i < VOCAB) {
        const float4* w4 = (const float4*)(W + (size_t)i * EMB);
        float4 buf[16];
        float s = 0.f;
        #pragma unroll
        for (int q = 0; q < 16; ++q) {
            float4 w = w4[q]; buf[q] = w;
            s += w.x * w.x + w.y * w.y + w.z * w.z + w.w * w.w;
        }
        float inv = 1.0f / sqrtf(s);
        invn[i] = inv;
        ushort4* dst = (ushort4*)(WB16 + (size_t)i * EMB);
        #pragma unroll
        for (int q = 0; q < 16; ++q) {
            float4 w = buf[q];
            ushort4 u;
            u.x = f2bf(w.x * inv); u.y = f2bf(w.y * inv);
            u.z = f2bf(w.z * inv); u.w = f2bf(w.w * inv);
            dst[q] = u;
        }
    }
    if (i < NROWS) {
        const float4* a4 = (const float4*)(x + (size_t)i * EMB);
        float4 buf[16];
        float s = 0.f;
        #pragma unroll
        for (int q = 0; q < 16; ++q) {
            float4 a = a4[q]; buf[q] = a;
            s += a.x * a.x + a.y * a.y + a.z * a.z + a.w * a.w;
        }
        normA[i] = sqrtf(s);
        ushort4* dst = (ushort4*)(A16 + (size_t)i * EMB);
        #pragma unroll
        for (int q = 0; q < 16; ++q) {
            float4 a = buf[q];
            ushort4 u;
            u.x = f2bf(a.x); u.y = f2bf(a.y); u.z = f2bf(a.z); u.w = f2bf(a.w);
            dst[q] = u;
        }
    }
}

// ---- pass1: grid-level fusion — compute blocks (bf16 MFMA -> pval u16)
//      run CONCURRENTLY with pure-zero blocks streaming the 1.048 GB out ----
// Block types interleave 25:32 per 57 so both are resident on every CU.
// Compute path identical to round 5 (4 frags, prefetch, subchunk u16 max);
// zero path is fill-kernel-shaped (tiny VGPR use, pure NT store loop).
__global__ __launch_bounds__(256) void pass1_kernel(
    const unsigned short* __restrict__ A16,
    const unsigned short* __restrict__ WB16,
    unsigned short* __restrict__ pval, float4* __restrict__ out4)
{
    const int bx = blockIdx.x;
    const int pat = bx / PAT, off = bx - pat * PAT;

    if (off >= 25) {
        // ---- zero block: 256 threads x 125 NT float4 stores = 512 KB ----
        const int zid = pat * 32 + (off - 25);          // 0..2047
        const f4nt z = {0.f, 0.f, 0.f, 0.f};
        float4* p = out4 + (size_t)zid * 256 + threadIdx.x;
        #pragma unroll 5
        for (int i = 0; i < 125; ++i)
            __builtin_nontemporal_store(z, (f4nt*)(p + (size_t)i * (NZ_BLOCKS * 256)));
        return;
    }

    // ---- compute block ----
    const int cid = pat * 25 + off;                     // 0..1599
    const int rowblk = cid & 31, chunk = cid >> 5;
    const int lane = threadIdx.x & 63, wid = threadIdx.x >> 6;
    const int lr = lane & 15, lg = lane >> 4;
    const int m0 = rowblk * 256 + wid * 64;
    const int n0 = chunk * CCOLS;

    bf16x8 a[4][2];
    #pragma unroll
    for (int r = 0; r < 4; ++r)
        #pragma unroll
        for (int kk = 0; kk < 2; ++kk)
            a[r][kk] = *(const bf16x8*)(A16 + (size_t)(m0 + r * 16 + lr) * EMB + kk * 32 + lg * 8);

    float best[4][4];
    #pragma unroll
    for (int r = 0; r < 4; ++r)
        #pragma unroll
        for (int j = 0; j < 4; ++j) best[r][j] = -3e38f;

    const unsigned short* wb = WB16 + (size_t)(n0 + lr) * EMB + lg * 8;
    bf16x8 b0 = *(const bf16x8*)(wb);
    bf16x8 b1 = *(const bf16x8*)(wb + 32);
    for (int t = 0; t < CTILES; ++t) {
        // prefetch next 16-col tile (last iter overruns 2KB into A16: harmless)
        const unsigned short* wn = wb + 16 * EMB;
        bf16x8 nb0 = *(const bf16x8*)(wn);
        bf16x8 nb1 = *(const bf16x8*)(wn + 32);
        #pragma unroll
        for (int r = 0; r < 4; ++r) {
            f32x4 acc = {0.f, 0.f, 0.f, 0.f};
            acc = __builtin_amdgcn_mfma_f32_16x16x32_bf16(a[r][0], b0, acc, 0, 0, 0);
            acc = __builtin_amdgcn_mfma_f32_16x16x32_bf16(a[r][1], b1, acc, 0, 0, 0);
            #pragma unroll
            for (int j = 0; j < 4; ++j) best[r][j] = fmaxf(best[r][j], acc[j]);
        }
        if ((t & 3) == 3) {   // subchunk (64 cols) boundary: reduce + u16 store
            const int sub = chunk * 10 + (t >> 2);
            #pragma unroll
            for (int r = 0; r < 4; ++r)
                #pragma unroll
                for (int j = 0; j < 4; ++j) {
                    float v = best[r][j];
                    v = fmaxf(v, __shfl_xor(v, 1));
                    v = fmaxf(v, __shfl_xor(v, 2));
                    v = fmaxf(v, __shfl_xor(v, 4));
                    v = fmaxf(v, __shfl_xor(v, 8));
                    if (lr == 0)
                        pval[(size_t)(m0 + r * 16 + lg * 4 + j) * SUBPAD + sub] =
                            (unsigned short)(enc_f32(v) >> 16);
                    best[r][j] = -3e38f;
                }
        }
        b0 = nb0; b1 = nb1;
        wb = wn;
    }
}

// ---- finalize: per-row select + exact rescore + scatter, one wave/row ----
// thr = max_approx - 0.009*|A| (2*2^-8*|A| bound + 15% slack, proven r3-r5).
// u16 compare (val+1)<<16 > thr_enc never false-prunes a truncated max, and
// always admits the max itself (>=1 survivor). Exact fp32 dot order and
// invn multiply are bit-identical to the r1-r5 validated path.
__global__ __launch_bounds__(64) void finalize_kernel(
    const float* __restrict__ x, const float* __restrict__ W,
    const float* __restrict__ invn, const unsigned short* __restrict__ pval,
    const float* __restrict__ normA, float* __restrict__ out)
{
    const int row = blockIdx.x;
    const int lane = threadIdx.x;
    __shared__ float xs[EMB];
    xs[lane] = x[(size_t)row * EMB + lane];

    const unsigned short* pr = pval + (size_t)row * SUBPAD + lane * 8;
    ushort4 v0 = *(const ushort4*)(pr);
    ushort4 v1 = *(const ushort4*)(pr + 4);
    unsigned short vals[8] = {v0.x, v0.y, v0.z, v0.w, v1.x, v1.y, v1.z, v1.w};

    unsigned mx = 0;
    #pragma unroll
    for (int k = 0; k < 8; ++k)
        if (lane * 8 + k < NSUB) mx = mx > (unsigned)vals[k] ? mx : (unsigned)vals[k];
    #pragma unroll
    for (int off = 1; off < 64; off <<= 1) {
        unsigned o = __shfl_xor(mx, off);
        mx = mx > o ? mx : o;
    }
    float thr = dec_f32(mx << 16) - 0.009f * normA[row];
    unsigned thr_enc = enc_f32(thr);

    __syncthreads();
    const float4* xs4 = (const float4*)xs;
    unsigned long long best = 0ull;

    #pragma unroll
    for (int k = 0; k < 8; ++k) {
        int sub = lane * 8 + k;
        bool c = (sub < NSUB) && ((((unsigned)vals[k] + 1u) << 16) > thr_enc);
        unsigned long long m = __ballot(c);
        while (m) {   // ~1.4 survivors/row on average
            int src = __ffsll((long long)m) - 1;
            m &= m - 1;
            unsigned v = ((unsigned)(src * 8 + k)) * 64u + (unsigned)lane;
            const float4* w4 = (const float4*)(W + (size_t)v * EMB);
            float p0 = 0.f, p1 = 0.f, p2 = 0.f, p3 = 0.f;
            #pragma unroll
            for (int q = 0; q < 16; ++q) {
                float4 aa = xs4[q]; float4 ww = w4[q];
                p0 = fmaf(aa.x, ww.x, p0);
                p1 = fmaf(aa.y, ww.y, p1);
                p2 = fmaf(aa.z, ww.z, p2);
                p3 = fmaf(aa.w, ww.w, p3);
            }
            float s = ((p0 + p1) + (p2 + p3)) * invn[v];
            // larger sim wins; equal sim -> larger ~v = smaller v (numpy tie-break)
            unsigned long long kk =
                ((unsigned long long)enc_f32(s) << 32) | (unsigned)(~v);
            best = best > kk ? best : kk;
        }
    }
    #pragma unroll
    for (int off = 1; off < 64; off <<= 1) {
        unsigned long long o = __shfl_xor(best, off);
        best = best > o ? best : o;
    }
    if (lane == 0)
        out[(size_t)row * VOCAB + (size_t)(unsigned)(~(unsigned)best)] = 1.0f;
}

extern "C" void kernel_launch(void* const* d_in, const int* in_sizes, int n_in,
                              void* d_out, int out_size, void* d_ws, size_t ws_size,
                              hipStream_t stream) {
    const float* x = (const float*)d_in[0];   // [2,4096,64]
    const float* W = (const float*)d_in[1];   // [32000,64]
    float* out = (float*)d_out;

    char* ws = (char*)d_ws;
    unsigned short* WB16 = (unsigned short*)(ws);                 // 4,096,000
    unsigned short* A16  = (unsigned short*)(ws + 4096000);       // 1,048,576
    float* invn          = (float*)(ws + 5144576);                //   128,000
    float* normA         = (float*)(ws + 5272576);                //    32,768
    unsigned short* pval = (unsigned short*)(ws + 5305344);       // 8,388,608
    // total ws use: 13,693,952 B

    setup_kernel<<<dim3((VOCAB + 255) / 256), dim3(256), 0, stream>>>(
        x, W, A16, WB16, invn, normA);

    pass1_kernel<<<dim3(TOTAL_BLOCKS), dim3(256), 0, stream>>>(
        A16, WB16, pval, (float4*)out);

    finalize_kernel<<<dim3(NROWS), dim3(64), 0, stream>>>(
        x, W, invn, pval, normA, out);
}